// Round 11
// baseline (250.228 us; speedup 1.0000x reference)
//
#include <hip/hip_runtime.h>
#include <stdint.h>

// ---------------------------------------------------------------------------
// StructureAE: h = x@W ; GAT edge softmax aggregate ; embed = leaky(out) ;
// recon = sigmoid(embed @ embed^T)
// N=10000, in_dim=512, out_dim=128, E=320000 (+N self loops)
// d_out = [recon (N*N f32), embed (N*128 f32)]
// ---------------------------------------------------------------------------

typedef __attribute__((ext_vector_type(8))) short short8v;  // 8 bf16 (4 VGPR)
typedef __attribute__((ext_vector_type(4))) float f32x4;

#define IN_DIM 512
#define OUT_DIM 128
#define NEG_ATT 0.5f
#define NEG_ACT 0.01f

__device__ __forceinline__ float leakyf(float v, float s) { return v >= 0.f ? v : s * v; }

__device__ __forceinline__ uint16_t f2bf(float v) {
  uint32_t u = __float_as_uint(v);
  u += 0x7FFFu + ((u >> 16) & 1u);   // round-to-nearest-even
  return (uint16_t)(u >> 16);
}
__device__ __forceinline__ float bf2f(uint16_t b) { return __uint_as_float(((uint32_t)b) << 16); }

// ---------------- h = x @ W (f32 compute, bf16 h store) + att dots + count --
__global__ __launch_bounds__(256) void k_h_gemm(const float* __restrict__ x,
                                                const float* __restrict__ W,
                                                const float* __restrict__ att_s_g,
                                                const float* __restrict__ att_d_g,
                                                const int* __restrict__ e_dst,
                                                int* __restrict__ cnt, int E,
                                                uint16_t* __restrict__ h16,
                                                float* __restrict__ a_src,
                                                float* __restrict__ a_dst, int N) {
  int tid = threadIdx.x;
  int tx = tid & 31, ty = tid >> 5;
  int row0 = blockIdx.x * 16 + ty * 2;
  int rc[2];
  #pragma unroll
  for (int r = 0; r < 2; ++r) rc[r] = (row0 + r < N) ? (row0 + r) : (N - 1);

  f32x4 acc[2];
  #pragma unroll
  for (int r = 0; r < 2; ++r) acc[r] = (f32x4){0.f, 0.f, 0.f, 0.f};

  for (int k = 0; k < IN_DIM; k += 4) {
    f32x4 wreg[4];
    #pragma unroll
    for (int kk = 0; kk < 4; ++kk)
      wreg[kk] = *(const f32x4*)&W[(size_t)(k + kk) * OUT_DIM + tx * 4];
    #pragma unroll
    for (int r = 0; r < 2; ++r) {
      f32x4 xv = *(const f32x4*)&x[(size_t)rc[r] * IN_DIM + k];
      #pragma unroll
      for (int kk = 0; kk < 4; ++kk) {
        acc[r][0] = fmaf(xv[kk], wreg[kk][0], acc[r][0]);
        acc[r][1] = fmaf(xv[kk], wreg[kk][1], acc[r][1]);
        acc[r][2] = fmaf(xv[kk], wreg[kk][2], acc[r][2]);
        acc[r][3] = fmaf(xv[kk], wreg[kk][3], acc[r][3]);
      }
    }
  }

  float atts[4], attd[4];
  #pragma unroll
  for (int j = 0; j < 4; ++j) { atts[j] = att_s_g[tx * 4 + j]; attd[j] = att_d_g[tx * 4 + j]; }
  #pragma unroll
  for (int r = 0; r < 2; ++r) {
    int row = row0 + r;
    float ps = 0.f, pd = 0.f;
    #pragma unroll
    for (int j = 0; j < 4; ++j) { ps = fmaf(acc[r][j], atts[j], ps); pd = fmaf(acc[r][j], attd[j], pd); }
    #pragma unroll
    for (int off = 16; off; off >>= 1) {   // reduce across the 32 tx lanes
      ps += __shfl_xor(ps, off);
      pd += __shfl_xor(pd, off);
    }
    if (row < N) {
      uint32_t lo = (uint32_t)f2bf(acc[r][0]) | ((uint32_t)f2bf(acc[r][1]) << 16);
      uint32_t hi = (uint32_t)f2bf(acc[r][2]) | ((uint32_t)f2bf(acc[r][3]) << 16);
      uint2 pk; pk.x = lo; pk.y = hi;
      *(uint2*)&h16[(size_t)row * OUT_DIM + tx * 4] = pk;
      if (tx == 0) { a_src[row] = ps; a_dst[row] = pd; }
    }
  }

  // fused edge counting (this block's 512-edge slice, coalesced)
  int e0 = blockIdx.x * 512 + tid;
  if (e0 < E) atomicAdd(&cnt[e_dst[e0]], 1);
  int e1 = e0 + 256;
  if (e1 < E) atomicAdd(&cnt[e_dst[e1]], 1);
}

// ---------------- CSR build --------------------------------------------------
__global__ __launch_bounds__(1024) void k_scan(const int* __restrict__ cnt,
                                               int* __restrict__ row_start,
                                               int* __restrict__ cursor, int N) {
  __shared__ int sd[1024];
  int t = threadIdx.x;
  const int CH = (N + 1023) >> 10;
  int base = t * CH;
  int s = 0;
  for (int k = 0; k < CH; ++k) { int i = base + k; if (i < N) s += cnt[i]; }
  sd[t] = s;
  __syncthreads();
  for (int off = 1; off < 1024; off <<= 1) {
    int v = (t >= off) ? sd[t - off] : 0;
    __syncthreads();
    sd[t] += v;
    __syncthreads();
  }
  int run = (t == 0) ? 0 : sd[t - 1];
  for (int k = 0; k < CH; ++k) {
    int i = base + k;
    if (i < N) { row_start[i] = run; cursor[i] = run; run += cnt[i]; }
  }
  if (t == 1023) row_start[N] = sd[1023];
}
__global__ void k_fill(const int* __restrict__ src, const int* __restrict__ dst,
                       int* __restrict__ cursor, int* __restrict__ csr, int E) {
  int e = blockIdx.x * blockDim.x + threadIdx.x;
  if (e < E) {
    int d = dst[e];
    int pos = atomicAdd(&cursor[d], 1);
    csr[pos] = src[e];
  }
}

// ---------------- per-dst softmax aggregation (one wave per node) -----------
__global__ __launch_bounds__(256) void k_aggregate(
    const uint16_t* __restrict__ h16, const float* __restrict__ a_src,
    const float* __restrict__ a_dst, const int* __restrict__ row_start,
    const int* __restrict__ csr, const float* __restrict__ bias,
    float* __restrict__ embed_out, uint16_t* __restrict__ ebf, int N, int NPAD) {
  int wid = (int)((blockIdx.x * blockDim.x + threadIdx.x) >> 6);
  int lane = threadIdx.x & 63;
  if (wid >= N) {
    if (wid < NPAD) {
      ebf[(size_t)wid * OUT_DIM + lane] = 0;
      ebf[(size_t)wid * OUT_DIM + 64 + lane] = 0;
    }
    return;
  }
  int i = wid;
  int s0 = row_start[i], s1 = row_start[i + 1];
  float adst = a_dst[i];
  float eself = leakyf(a_src[i] + adst, NEG_ATT);
  float m = eself;
  for (int k = s0 + lane; k < s1; k += 64) {
    float e = leakyf(a_src[csr[k]] + adst, NEG_ATT);
    m = fmaxf(m, e);
  }
  #pragma unroll
  for (int off = 32; off; off >>= 1) m = fmaxf(m, __shfl_xor(m, off));
  float dsum = 0.f;
  for (int k = s0 + lane; k < s1; k += 64) {
    float e = leakyf(a_src[csr[k]] + adst, NEG_ATT);
    dsum += __expf(e - m);
  }
  #pragma unroll
  for (int off = 32; off; off >>= 1) dsum += __shfl_xor(dsum, off);
  dsum += __expf(eself - m);
  float inv = 1.0f / dsum;
  float wself = __expf(eself - m) * inv;
  float acc0 = bf2f(h16[(size_t)i * OUT_DIM + lane]) * wself;
  float acc1 = bf2f(h16[(size_t)i * OUT_DIM + 64 + lane]) * wself;
  #pragma unroll 4
  for (int k = s0; k < s1; ++k) {
    int s = csr[k];  // uniform across wave
    float w = __expf(leakyf(a_src[s] + adst, NEG_ATT) - m) * inv;
    acc0 = fmaf(bf2f(h16[(size_t)s * OUT_DIM + lane]), w, acc0);
    acc1 = fmaf(bf2f(h16[(size_t)s * OUT_DIM + 64 + lane]), w, acc1);
  }
  float o0 = leakyf(acc0 + bias[lane], NEG_ACT);
  float o1 = leakyf(acc1 + bias[64 + lane], NEG_ACT);
  embed_out[(size_t)i * OUT_DIM + lane] = o0;
  embed_out[(size_t)i * OUT_DIM + 64 + lane] = o1;
  ebf[(size_t)i * OUT_DIM + lane] = f2bf(o0);
  ebf[(size_t)i * OUT_DIM + 64 + lane] = f2bf(o1);
}

// ---------------- recon: ROW-SLAB STREAMING ---------------------------------
// EXPERIMENT: each output row is written by exactly ONE block, left-to-right
// sequentially (the fill kernel's DRAM-page-friendly pattern), instead of 79
// scattered 512B tile fragments per row.
// Block = 256 thr (4 waves) owns 16 output rows x a half-width column range.
// Grid = 625 slabs x 2 halves = 1250 (makespan tail ~2.5%).
// Per 128-col strip: stage 128 col-nodes -> LDS (XOR swizzle, r5-proven),
// each wave computes 2 col-tiles with OPERAND-SWAPPED MFMA:
//   D = mfma(colfrag, rowfrag): D[m][n] = recon[rowBase+n][stripBase+m]
//   -> lane L, regs q: out row = rowBase+(L&15), cols = tile+( L>>4)*4+q
//   (4 consecutive cols per lane) -> sigmoid -> f32x4 deposit into sO.
// Readback: 512 B/row segments at monotonically increasing addresses.
// 2 barriers/strip. LDS 41 KB -> 3 blocks/CU. Row-frags hoisted.
// A/B frag layout (16x16x32): row/col = lane&15, k = 8*(lane>>4)+j  (same
// loader for both operands); C/D: col = lane&15, row = (lane>>4)*4 + reg.
__global__ __launch_bounds__(256, 4) void k_recon(const uint16_t* __restrict__ ebf,
                                                  float* __restrict__ out,
                                                  int N, int nStrips) {
  __shared__ __align__(16) uint16_t sB[128 * OUT_DIM];  // 32 KB col-node strip
  __shared__ __align__(16) float sO[16 * 132];          // 8.25 KB out slab

  int tid = threadIdx.x;
  int wid = tid >> 6, lane = tid & 63;
  int r16 = lane & 15, kg = lane >> 4;

  int slab = blockIdx.x >> 1;          // 0..624
  int half = blockIdx.x & 1;           // column half
  int rowBase = slab * 16;
  int sH = nStrips >> 1;               // 39
  int strip0 = half ? (nStrips - sH) : 0;       // 0 or 40
  int strip1 = half ? nStrips : (nStrips - sH); // 40 or 79

  // row-node fragments (the MFMA B operand), hoisted: kc = 0..3
  short8v rowfrag[4];
  #pragma unroll
  for (int kc = 0; kc < 4; ++kc)
    rowfrag[kc] = *(const short8v*)&ebf[(size_t)(rowBase + r16) * OUT_DIM + kc * 32 + kg * 8];

  for (int strip = strip0; strip < strip1; ++strip) {
    int colBase = strip * 128;
    // ---- stage 128 col-nodes (coalesced, XOR swizzle): 2048 x 16B ----
    #pragma unroll
    for (int p = 0; p < 8; ++p) {
      int i2 = p * 256 + tid;
      int row = i2 >> 4, slot = i2 & 15;
      f32x4 vb = *(const f32x4*)&ebf[(size_t)(colBase + row) * OUT_DIM + slot * 8];
      int ss = slot ^ (row & 7);
      *(f32x4*)&sB[row * OUT_DIM + ss * 8] = vb;
    }
    __syncthreads();
    // ---- compute: 8 col-tiles / 4 waves = 2 per wave ----
    #pragma unroll
    for (int tt = 0; tt < 2; ++tt) {
      int t = wid * 2 + tt;
      f32x4 acc = (f32x4){0.f, 0.f, 0.f, 0.f};
      #pragma unroll
      for (int kc = 0; kc < 4; ++kc) {
        int cn = t * 16 + r16;                 // col-node within strip
        int ss = (kc * 4 + kg) ^ (cn & 7);
        short8v cf = *(const short8v*)&sB[cn * OUT_DIM + ss * 8];
        acc = __builtin_amdgcn_mfma_f32_16x16x32_bf16(cf, rowfrag[kc], acc, 0, 0, 0);
      }
      f32x4 sg;
      #pragma unroll
      for (int q = 0; q < 4; ++q) sg[q] = 1.0f / (1.0f + __expf(-acc[q]));
      // lane L: out-row r16, cols t*16 + kg*4 .. +3 (16B-aligned, 2-way bank)
      *(f32x4*)&sO[r16 * 132 + t * 16 + kg * 4] = sg;
    }
    __syncthreads();
    // ---- readback + nt store: 16 rows x 512 B, sequential per row ----
    #pragma unroll
    for (int it = 0; it < 2; ++it) {
      int row = it * 8 + (tid >> 5);
      int c4 = tid & 31;
      f32x4 v = *(const f32x4*)&sO[row * 132 + c4 * 4];
      int col = colBase + c4 * 4;
      size_t o = (size_t)(rowBase + row) * N + col;
      if (col + 3 < N) {
        __builtin_nontemporal_store(v, (f32x4*)&out[o]);
      } else {
        #pragma unroll
        for (int j = 0; j < 4; ++j)
          if (col + j < N) __builtin_nontemporal_store(v[j], &out[o + j]);
      }
    }
    // no trailing barrier needed: next stage writes sB only after all waves
    // passed the post-compute barrier (sB reads done); next sO deposits come
    // after next post-stage barrier, and this wave's sO reads precede it.
  }
}

// ---------------------------------------------------------------------------
extern "C" void kernel_launch(void* const* d_in, const int* in_sizes, int n_in,
                              void* d_out, int out_size, void* d_ws, size_t ws_size,
                              hipStream_t stream) {
  const float* x = (const float*)d_in[0];
  const int* ei = (const int*)d_in[1];
  const float* W = (const float*)d_in[2];
  const float* att_s = (const float*)d_in[3];
  const float* att_d = (const float*)d_in[4];
  const float* bias = (const float*)d_in[5];

  const int N = in_sizes[0] / IN_DIM;        // 10000
  const int E = in_sizes[1] / 2;             // 320000
  const int NB = (N + 127) / 128;            // 79 col strips
  const int NPAD = NB * 128;                 // 10112

  float* out = (float*)d_out;
  float* embed_out = out + (size_t)N * N;

  // workspace layout (all segments 16B-aligned)
  uint16_t* h16 = (uint16_t*)d_ws;              // N*128 bf16
  float* a_src = (float*)(h16 + (size_t)N * OUT_DIM);  // N
  float* a_dst = a_src + N;                     // N
  int* cnt = (int*)(a_dst + N);                 // N
  int* row_start = cnt + N;                     // N+4 (padded)
  int* cursor = row_start + (N + 4);            // N
  int* csr = cursor + N;                        // E
  uint16_t* ebf = (uint16_t*)(csr + E);         // NPAD*128 bf16

  const int* e_src = ei;
  const int* e_dst = ei + E;

  hipMemsetAsync(cnt, 0, (size_t)N * sizeof(int), stream);
  k_h_gemm<<<dim3((N + 15) / 16), 256, 0, stream>>>(x, W, att_s, att_d,
                                                    e_dst, cnt, E, h16, a_src, a_dst, N);
  k_scan<<<dim3(1), 1024, 0, stream>>>(cnt, row_start, cursor, N);
  k_fill<<<dim3((E + 255) / 256), 256, 0, stream>>>(e_src, e_dst, cursor, csr, E);
  k_aggregate<<<dim3((NPAD * 64 + 255) / 256), 256, 0, stream>>>(
      h16, a_src, a_dst, row_start, csr, bias, embed_out, ebf, N, NPAD);
  const int nSlabs = N / 16;                  // 625
  k_recon<<<dim3(nSlabs * 2), 256, 0, stream>>>(ebf, out, N, NB);
}

// Round 13
// 224.568 us; speedup vs baseline: 1.1143x; 1.1143x over previous
//
#include <hip/hip_runtime.h>
#include <stdint.h>

// ---------------------------------------------------------------------------
// StructureAE: h = x@W ; GAT edge softmax aggregate ; embed = leaky(out) ;
// recon = sigmoid(embed @ embed^T)
// N=10000, in_dim=512, out_dim=128, E=320000 (+N self loops)
// d_out = [recon (N*N f32), embed (N*128 f32)]
// ROUND-7 PROVEN CONFIGURATION (best replay-validated: 225.5 us).
// r12's scan-free bucket CSR diverged across graph replays (nondeterministic
// csr fill) -- reverted to the two-pass CSR build which passed post-timing
// validation in rounds 6-11.
// ---------------------------------------------------------------------------

typedef __attribute__((ext_vector_type(8))) short short8v;  // 8 bf16 (4 VGPR)
typedef __attribute__((ext_vector_type(4))) float f32x4;

#define IN_DIM 512
#define OUT_DIM 128
#define NEG_ATT 0.5f
#define NEG_ACT 0.01f

__device__ __forceinline__ float leakyf(float v, float s) { return v >= 0.f ? v : s * v; }

__device__ __forceinline__ uint16_t f2bf(float v) {
  uint32_t u = __float_as_uint(v);
  u += 0x7FFFu + ((u >> 16) & 1u);   // round-to-nearest-even
  return (uint16_t)(u >> 16);
}
__device__ __forceinline__ float bf2f(uint16_t b) { return __uint_as_float(((uint32_t)b) << 16); }

// ---------------- h = x @ W (f32 compute, bf16 h store) + att dots + count --
// 16 rows/block, 625 blocks. tx = 32 col-groups x 4 f32; ty = 8 row-groups x
// 2 rows. W rows coalesced (L2-resident); x reads wave-broadcast.
// h stored as bf16 (halves the aggregate gather traffic).
// Epilogue also counts this block's 512-edge slice into cnt (k_count fused).
__global__ __launch_bounds__(256) void k_h_gemm(const float* __restrict__ x,
                                                const float* __restrict__ W,
                                                const float* __restrict__ att_s_g,
                                                const float* __restrict__ att_d_g,
                                                const int* __restrict__ e_dst,
                                                int* __restrict__ cnt, int E,
                                                uint16_t* __restrict__ h16,
                                                float* __restrict__ a_src,
                                                float* __restrict__ a_dst, int N) {
  int tid = threadIdx.x;
  int tx = tid & 31, ty = tid >> 5;
  int row0 = blockIdx.x * 16 + ty * 2;
  int rc[2];
  #pragma unroll
  for (int r = 0; r < 2; ++r) rc[r] = (row0 + r < N) ? (row0 + r) : (N - 1);

  f32x4 acc[2];
  #pragma unroll
  for (int r = 0; r < 2; ++r) acc[r] = (f32x4){0.f, 0.f, 0.f, 0.f};

  for (int k = 0; k < IN_DIM; k += 4) {
    f32x4 wreg[4];
    #pragma unroll
    for (int kk = 0; kk < 4; ++kk)
      wreg[kk] = *(const f32x4*)&W[(size_t)(k + kk) * OUT_DIM + tx * 4];
    #pragma unroll
    for (int r = 0; r < 2; ++r) {
      f32x4 xv = *(const f32x4*)&x[(size_t)rc[r] * IN_DIM + k];
      #pragma unroll
      for (int kk = 0; kk < 4; ++kk) {
        acc[r][0] = fmaf(xv[kk], wreg[kk][0], acc[r][0]);
        acc[r][1] = fmaf(xv[kk], wreg[kk][1], acc[r][1]);
        acc[r][2] = fmaf(xv[kk], wreg[kk][2], acc[r][2]);
        acc[r][3] = fmaf(xv[kk], wreg[kk][3], acc[r][3]);
      }
    }
  }

  float atts[4], attd[4];
  #pragma unroll
  for (int j = 0; j < 4; ++j) { atts[j] = att_s_g[tx * 4 + j]; attd[j] = att_d_g[tx * 4 + j]; }
  #pragma unroll
  for (int r = 0; r < 2; ++r) {
    int row = row0 + r;
    float ps = 0.f, pd = 0.f;
    #pragma unroll
    for (int j = 0; j < 4; ++j) { ps = fmaf(acc[r][j], atts[j], ps); pd = fmaf(acc[r][j], attd[j], pd); }
    #pragma unroll
    for (int off = 16; off; off >>= 1) {   // reduce across the 32 tx lanes
      ps += __shfl_xor(ps, off);
      pd += __shfl_xor(pd, off);
    }
    if (row < N) {
      uint32_t lo = (uint32_t)f2bf(acc[r][0]) | ((uint32_t)f2bf(acc[r][1]) << 16);
      uint32_t hi = (uint32_t)f2bf(acc[r][2]) | ((uint32_t)f2bf(acc[r][3]) << 16);
      uint2 pk; pk.x = lo; pk.y = hi;
      *(uint2*)&h16[(size_t)row * OUT_DIM + tx * 4] = pk;
      if (tx == 0) { a_src[row] = ps; a_dst[row] = pd; }
    }
  }

  // fused edge counting (this block's 512-edge slice, coalesced)
  int e0 = blockIdx.x * 512 + tid;
  if (e0 < E) atomicAdd(&cnt[e_dst[e0]], 1);
  int e1 = e0 + 256;
  if (e1 < E) atomicAdd(&cnt[e_dst[e1]], 1);
}

// ---------------- CSR build --------------------------------------------------
__global__ __launch_bounds__(1024) void k_scan(const int* __restrict__ cnt,
                                               int* __restrict__ row_start,
                                               int* __restrict__ cursor, int N) {
  __shared__ int sd[1024];
  int t = threadIdx.x;
  const int CH = (N + 1023) >> 10;
  int base = t * CH;
  int s = 0;
  for (int k = 0; k < CH; ++k) { int i = base + k; if (i < N) s += cnt[i]; }
  sd[t] = s;
  __syncthreads();
  for (int off = 1; off < 1024; off <<= 1) {
    int v = (t >= off) ? sd[t - off] : 0;
    __syncthreads();
    sd[t] += v;
    __syncthreads();
  }
  int run = (t == 0) ? 0 : sd[t - 1];
  for (int k = 0; k < CH; ++k) {
    int i = base + k;
    if (i < N) { row_start[i] = run; cursor[i] = run; run += cnt[i]; }
  }
  if (t == 1023) row_start[N] = sd[1023];
}
__global__ void k_fill(const int* __restrict__ src, const int* __restrict__ dst,
                       int* __restrict__ cursor, int* __restrict__ csr, int E) {
  int e = blockIdx.x * blockDim.x + threadIdx.x;
  if (e < E) {
    int d = dst[e];
    int pos = atomicAdd(&cursor[d], 1);
    csr[pos] = src[e];
  }
}

// ---------------- per-dst softmax aggregation (one wave per node) -----------
// h gathered as bf16. Waves i in [N, NPAD) zero their ebf row (k_pad fused).
__global__ __launch_bounds__(256) void k_aggregate(
    const uint16_t* __restrict__ h16, const float* __restrict__ a_src,
    const float* __restrict__ a_dst, const int* __restrict__ row_start,
    const int* __restrict__ csr, const float* __restrict__ bias,
    float* __restrict__ embed_out, uint16_t* __restrict__ ebf, int N, int NPAD) {
  int wid = (int)((blockIdx.x * blockDim.x + threadIdx.x) >> 6);
  int lane = threadIdx.x & 63;
  if (wid >= N) {
    if (wid < NPAD) {
      ebf[(size_t)wid * OUT_DIM + lane] = 0;
      ebf[(size_t)wid * OUT_DIM + 64 + lane] = 0;
    }
    return;
  }
  int i = wid;
  int s0 = row_start[i], s1 = row_start[i + 1];
  float adst = a_dst[i];
  float eself = leakyf(a_src[i] + adst, NEG_ATT);
  float m = eself;
  for (int k = s0 + lane; k < s1; k += 64) {
    float e = leakyf(a_src[csr[k]] + adst, NEG_ATT);
    m = fmaxf(m, e);
  }
  #pragma unroll
  for (int off = 32; off; off >>= 1) m = fmaxf(m, __shfl_xor(m, off));
  float dsum = 0.f;
  for (int k = s0 + lane; k < s1; k += 64) {
    float e = leakyf(a_src[csr[k]] + adst, NEG_ATT);
    dsum += __expf(e - m);
  }
  #pragma unroll
  for (int off = 32; off; off >>= 1) dsum += __shfl_xor(dsum, off);
  dsum += __expf(eself - m);
  float inv = 1.0f / dsum;
  float wself = __expf(eself - m) * inv;
  float acc0 = bf2f(h16[(size_t)i * OUT_DIM + lane]) * wself;
  float acc1 = bf2f(h16[(size_t)i * OUT_DIM + 64 + lane]) * wself;
  #pragma unroll 4
  for (int k = s0; k < s1; ++k) {
    int s = csr[k];  // uniform across wave
    float w = __expf(leakyf(a_src[s] + adst, NEG_ATT) - m) * inv;
    acc0 = fmaf(bf2f(h16[(size_t)s * OUT_DIM + lane]), w, acc0);
    acc1 = fmaf(bf2f(h16[(size_t)s * OUT_DIM + 64 + lane]), w, acc1);
  }
  float o0 = leakyf(acc0 + bias[lane], NEG_ACT);
  float o1 = leakyf(acc1 + bias[64 + lane], NEG_ACT);
  embed_out[(size_t)i * OUT_DIM + lane] = o0;
  embed_out[(size_t)i * OUT_DIM + 64 + lane] = o1;
  ebf[(size_t)i * OUT_DIM + lane] = f2bf(o0);
  ebf[(size_t)i * OUT_DIM + 64 + lane] = f2bf(o1);
}

// ---------------- recon = sigmoid(embed @ embed^T), LDS-staged MFMA ---------
// Round-7 structure VERBATIM: 128x128 tile, 8 waves, 48 KB LDS (sA full-K
// 32 KB; sB K-half 16 KB restaged) -> 3 blocks/CU; XOR-swizzled staging;
// sO aliases sA; 512 B contiguous NONTEMPORAL row-segment stores (r9: nt >
// plain by 30 us; r10: 1024B segments null; r11: row-streaming regressed).
// mfma_f32_16x16x32_bf16 A/B: lane holds row/col = lane&15, k = 8*(lane>>4)+j;
// C/D: col = lane&15, row = (lane>>4)*4 + reg.
__global__ __launch_bounds__(512, 6) void k_recon(const uint16_t* __restrict__ ebf,
                                                  float* __restrict__ out,
                                                  int N, int nb) {
  __shared__ __align__(16) unsigned char smem[49152];
  uint16_t* sA = (uint16_t*)smem;            // [128][128] bf16, swizzled
  uint16_t* sB = (uint16_t*)(smem + 32768);  // [128][64] bf16 (K-half), swizzled
  float* sO = (float*)smem;                  // [64][128] f32 (aliases sA)

  int tid = threadIdx.x;
  int wid = tid >> 6, lane = tid & 63;
  int wr = wid >> 2, wc = wid & 3;
  int r16 = lane & 15, kg = lane >> 4;

  // bijective XCD swizzle (m204): per-XCD contiguous tile range,
  // row-panel-major; B panel (2.6 MB) stays L2-resident per XCD.
  int nwg = nb * nb;
  int q = nwg >> 3, r8 = nwg & 7;
  int orig = blockIdx.x;
  int xcd = orig & 7, sub = orig >> 3;
  int swz = (xcd < r8 ? xcd * (q + 1) : r8 * (q + 1) + (xcd - r8) * q) + sub;
  int by = swz / nb, bx = swz - by * nb;
  int rowBlk = by * 128, colBlk = bx * 128;

  // ---- stage A tile (full K) + B tile K-half 0 ----
  #pragma unroll
  for (int p = 0; p < 4; ++p) {
    int i2 = p * 512 + tid;          // 2048 x 16B chunks
    int row = i2 >> 4, slot = i2 & 15;
    f32x4 va = *(const f32x4*)&ebf[(size_t)(rowBlk + row) * OUT_DIM + slot * 8];
    int ss = slot ^ (row & 7);
    *(f32x4*)&sA[row * OUT_DIM + ss * 8] = va;
  }
  #pragma unroll
  for (int p = 0; p < 2; ++p) {
    int i2 = p * 512 + tid;          // 1024 x 16B chunks
    int row = i2 >> 3, slot = i2 & 7;
    f32x4 vb = *(const f32x4*)&ebf[(size_t)(colBlk + row) * OUT_DIM + slot * 8];
    int ss = slot ^ (row & 7);
    *(f32x4*)&sB[row * 64 + ss * 8] = vb;
  }
  __syncthreads();

  // ---- MFMA: wave computes 64x32; K=128 as 2 halves x 2 chunks of 32 ----
  int rowWl = wr * 64, colWl = wc * 32;
  f32x4 acc[4][2];
  #pragma unroll
  for (int a = 0; a < 4; ++a)
    #pragma unroll
    for (int b = 0; b < 2; ++b) acc[a][b] = (f32x4){0.f, 0.f, 0.f, 0.f};

  #pragma unroll
  for (int half = 0; half < 2; ++half) {
    #pragma unroll
    for (int kch = 0; kch < 2; ++kch) {
      int s16 = (half * 2 + kch) * 4 + kg;   // absolute K-slot for A (0..15)
      int khalf = kch * 4 + kg;              // within-half K-slot for B (0..7)
      short8v bfr[2];
      #pragma unroll
      for (int tj = 0; tj < 2; ++tj) {
        int rw = colWl + tj * 16 + r16;
        int ss = khalf ^ (rw & 7);
        bfr[tj] = *(const short8v*)&sB[rw * 64 + ss * 8];
      }
      #pragma unroll
      for (int ti = 0; ti < 4; ++ti) {
        int rw = rowWl + ti * 16 + r16;
        int ss = s16 ^ (rw & 7);
        short8v af = *(const short8v*)&sA[rw * OUT_DIM + ss * 8];
        #pragma unroll
        for (int tj = 0; tj < 2; ++tj)
          acc[ti][tj] = __builtin_amdgcn_mfma_f32_16x16x32_bf16(af, bfr[tj], acc[ti][tj], 0, 0, 0);
      }
    }
    if (half == 0) {   // restage B with K-half 1
      __syncthreads();
      #pragma unroll
      for (int p = 0; p < 2; ++p) {
        int i2 = p * 512 + tid;
        int row = i2 >> 3, slot = i2 & 7;
        f32x4 vb = *(const f32x4*)&ebf[(size_t)(colBlk + row) * OUT_DIM + 64 + slot * 8];
        int ss = slot ^ (row & 7);
        *(f32x4*)&sB[row * 64 + ss * 8] = vb;
      }
      __syncthreads();
    }
  }
  __syncthreads();   // sA reads done; safe to overwrite via sO

  // ---- epilogue: 2 slices of 64 rows via sO (aliases sA region) ----
  bool colFull = (colBlk + 128 <= N);
  #pragma unroll
  for (int s = 0; s < 2; ++s) {
    if (wr == s) {
      #pragma unroll
      for (int ti = 0; ti < 4; ++ti)
        #pragma unroll
        for (int tj = 0; tj < 2; ++tj) {
          int col = wc * 32 + tj * 16 + r16;
          int slot = col >> 2, within = col & 3;
          int sslot = slot ^ (kg << 1);
          #pragma unroll
          for (int qq = 0; qq < 4; ++qq)
            sO[(ti * 16 + kg * 4 + qq) * 128 + sslot * 4 + within] = acc[ti][tj][qq];
        }
    }
    __syncthreads();
    int srow0 = rowBlk + s * 64;
    #pragma unroll
    for (int p = 0; p < 4; ++p) {
      int i2 = p * 512 + tid;
      int row = i2 >> 5, c = i2 & 31;   // 32 lanes x 16B = 512 B per row segment
      int sslot = c ^ (((row >> 2) & 3) << 1);
      f32x4 v = *(const f32x4*)&sO[row * 128 + sslot * 4];
      #pragma unroll
      for (int j = 0; j < 4; ++j) v[j] = 1.0f / (1.0f + __expf(-v[j]));
      int rr = srow0 + row;
      if (rr < N) {
        int col = colBlk + c * 4;
        if (colFull) {
          __builtin_nontemporal_store(v, (f32x4*)&out[(size_t)rr * N + col]);
        } else {
          #pragma unroll
          for (int j = 0; j < 4; ++j)
            if (col + j < N) __builtin_nontemporal_store(v[j], &out[(size_t)rr * N + col + j]);
        }
      }
    }
    if (s == 0) __syncthreads();   // slice-0 reads done before slice-1 deposit
  }
}

// ---------------------------------------------------------------------------
extern "C" void kernel_launch(void* const* d_in, const int* in_sizes, int n_in,
                              void* d_out, int out_size, void* d_ws, size_t ws_size,
                              hipStream_t stream) {
  const float* x = (const float*)d_in[0];
  const int* ei = (const int*)d_in[1];
  const float* W = (const float*)d_in[2];
  const float* att_s = (const float*)d_in[3];
  const float* att_d = (const float*)d_in[4];
  const float* bias = (const float*)d_in[5];

  const int N = in_sizes[0] / IN_DIM;        // 10000
  const int E = in_sizes[1] / 2;             // 320000
  const int NB = (N + 127) / 128;            // 79
  const int NPAD = NB * 128;                 // 10112

  float* out = (float*)d_out;
  float* embed_out = out + (size_t)N * N;

  // workspace layout (all segments 16B-aligned)
  uint16_t* h16 = (uint16_t*)d_ws;              // N*128 bf16
  float* a_src = (float*)(h16 + (size_t)N * OUT_DIM);  // N
  float* a_dst = a_src + N;                     // N
  int* cnt = (int*)(a_dst + N);                 // N
  int* row_start = cnt + N;                     // N+4 (padded)
  int* cursor = row_start + (N + 4);            // N
  int* csr = cursor + N;                        // E
  uint16_t* ebf = (uint16_t*)(csr + E);         // NPAD*128 bf16

  const int* e_src = ei;
  const int* e_dst = ei + E;

  hipMemsetAsync(cnt, 0, (size_t)N * sizeof(int), stream);
  k_h_gemm<<<dim3((N + 15) / 16), 256, 0, stream>>>(x, W, att_s, att_d,
                                                    e_dst, cnt, E, h16, a_src, a_dst, N);
  k_scan<<<dim3(1), 1024, 0, stream>>>(cnt, row_start, cursor, N);
  k_fill<<<dim3((E + 255) / 256), 256, 0, stream>>>(e_src, e_dst, cursor, csr, E);
  k_aggregate<<<dim3((NPAD * 64 + 255) / 256), 256, 0, stream>>>(
      h16, a_src, a_dst, row_start, csr, bias, embed_out, ebf, N, NPAD);
  k_recon<<<dim3(NB * NB), 512, 0, stream>>>(ebf, out, N, NB);
}